// Round 1
// baseline (270.803 us; speedup 1.0000x reference)
//
#include <hip/hip_runtime.h>
#include <math.h>

#define DIM 128
#define TEMP_INV 10.0f

// Kernel 1: inv_norm[row] = 1/||x[row]||, one wave (64 lanes) per row.
// Also zeroes d_out[0] (harness re-poisons it to 0xAA before timed replays).
__global__ __launch_bounds__(256) void norm_kernel(const float* __restrict__ x,
                                                   float* __restrict__ inv_norm,
                                                   float* __restrict__ out,
                                                   int N) {
    if (blockIdx.x == 0 && threadIdx.x == 0) out[0] = 0.0f;
    int wave = threadIdx.x >> 6;           // 0..3
    int lane = threadIdx.x & 63;
    int row  = blockIdx.x * 4 + wave;
    if (row >= N) return;
    const float2 v = *(const float2*)(x + (size_t)row * DIM + lane * 2);
    float s = v.x * v.x + v.y * v.y;
    s += __shfl_xor(s, 32);
    s += __shfl_xor(s, 16);
    s += __shfl_xor(s, 8);
    s += __shfl_xor(s, 4);
    s += __shfl_xor(s, 2);
    s += __shfl_xor(s, 1);
    if (lane == 0) inv_norm[row] = rsqrtf(s);
}

// Kernel 2: one block (256 threads = 8 groups of 32 lanes) per anchor.
// Each 32-lane group processes one sample per iteration: 32 lanes x float4
// covers the full 128-float row as one contiguous 512B segment.
__global__ __launch_bounds__(256) void loss_kernel(const float* __restrict__ x,
                                                   const int* __restrict__ y,
                                                   const int* __restrict__ anchors,
                                                   const int* __restrict__ sampled,
                                                   const float* __restrict__ inv_norm,
                                                   float* __restrict__ out,
                                                   int S) {
    int a     = blockIdx.x;
    int tid   = threadIdx.x;
    int lane  = tid & 31;    // lane within 32-group
    int group = tid >> 5;    // 0..7

    int   anchor = anchors[a];
    int   ya     = y[anchor];
    float inv_a  = inv_norm[anchor];
    float4 av = *(const float4*)(x + (size_t)anchor * DIM + lane * 4);
    av.x *= inv_a; av.y *= inv_a; av.z *= inv_a; av.w *= inv_a;

    float num = 0.0f, den = 0.0f, cnt = 0.0f;
    const int* samp = sampled + (size_t)a * S;

#pragma unroll 4
    for (int s = group; s < S; s += 8) {
        int   sidx  = samp[s];                 // broadcast across 32 lanes
        float inv_s = inv_norm[sidx];
        int   ys    = y[sidx];
        const float4 sv = *(const float4*)(x + (size_t)sidx * DIM + lane * 4);
        float d = av.x * sv.x + av.y * sv.y + av.z * sv.z + av.w * sv.w;
        // butterfly over the 32-lane group (masks < 32 stay within half-wave)
        d += __shfl_xor(d, 16);
        d += __shfl_xor(d, 8);
        d += __shfl_xor(d, 4);
        d += __shfl_xor(d, 2);
        d += __shfl_xor(d, 1);
        float e = __expf(d * inv_s * TEMP_INV);   // inv_a already folded into av
        den += e;
        bool pos = (ys == ya);
        num += pos ? e : 0.0f;
        cnt += pos ? 1.0f : 0.0f;
    }

    // all 32 lanes of a group hold identical accumulators; reduce 8 groups
    __shared__ float s_num[8], s_den[8], s_cnt[8];
    if (lane == 0) { s_num[group] = num; s_den[group] = den; s_cnt[group] = cnt; }
    __syncthreads();
    if (tid == 0) {
        float tn = 0.0f, td = 0.0f, tc = 0.0f;
        for (int g = 0; g < 8; ++g) { tn += s_num[g]; td += s_den[g]; tc += s_cnt[g]; }
        float loss = 0.0f;
        if (tc > 0.0f) loss = -__logf(tn / td) / tc;
        atomicAdd(out, loss);
    }
}

extern "C" void kernel_launch(void* const* d_in, const int* in_sizes, int n_in,
                              void* d_out, int out_size, void* d_ws, size_t ws_size,
                              hipStream_t stream) {
    const float* x       = (const float*)d_in[0];
    const int*   y       = (const int*)d_in[1];
    const int*   anchors = (const int*)d_in[2];
    const int*   sampled = (const int*)d_in[3];

    int N = in_sizes[1];              // y has N elements
    int A = in_sizes[2];              // anchors
    int S = in_sizes[3] / A;          // samples per anchor

    float* inv_norm = (float*)d_ws;   // N floats (~400 KB)
    float* out      = (float*)d_out;

    int norm_blocks = (N + 3) / 4;    // 4 rows (waves) per 256-thread block
    norm_kernel<<<norm_blocks, 256, 0, stream>>>(x, inv_norm, out, N);
    loss_kernel<<<A, 256, 0, stream>>>(x, y, anchors, sampled, inv_norm, out, S);
}

// Round 2
// 199.204 us; speedup vs baseline: 1.3594x; 1.3594x over previous
//
#include <hip/hip_runtime.h>
#include <hip/hip_bf16.h>
#include <math.h>

#define DIM 128
#define TEMP_INV 10.0f

static __device__ __forceinline__ unsigned short f2bf(float f) {
    __hip_bfloat16 h = __float2bfloat16(f);           // round-to-nearest
    return *reinterpret_cast<unsigned short*>(&h);
}
static __device__ __forceinline__ void unpack2(unsigned int u, float& lo, float& hi) {
    lo = __uint_as_float(u << 16);                    // exact bf16->f32
    hi = __uint_as_float(u & 0xffff0000u);
}

// ---------------- bf16 fast path ----------------

// Normalize rows to bf16: block 256 = 8 groups of 32 lanes, one row per group.
// Also zeroes d_out[0] (harness re-poisons to 0xAA before timed replays).
__global__ __launch_bounds__(256) void norm_bf16_kernel(const float* __restrict__ x,
                                                        unsigned short* __restrict__ xn,
                                                        float* __restrict__ out,
                                                        int N) {
    if (blockIdx.x == 0 && threadIdx.x == 0) out[0] = 0.0f;
    int lane = threadIdx.x & 31;
    int grp  = threadIdx.x >> 5;
    int row  = blockIdx.x * 8 + grp;
    if (row >= N) return;
    float4 v = *(const float4*)(x + (size_t)row * DIM + lane * 4);
    float s = v.x*v.x + v.y*v.y + v.z*v.z + v.w*v.w;
    s += __shfl_xor(s, 16); s += __shfl_xor(s, 8); s += __shfl_xor(s, 4);
    s += __shfl_xor(s, 2);  s += __shfl_xor(s, 1);
    float inv = rsqrtf(s);
    ushort4 u;
    u.x = f2bf(v.x * inv); u.y = f2bf(v.y * inv);
    u.z = f2bf(v.z * inv); u.w = f2bf(v.w * inv);
    *(ushort4*)(xn + (size_t)row * DIM + lane * 4) = u;
}

// One block (256 thr = 16 groups of 16 lanes) per anchor; one sample per group
// per iteration. Lane loads uint4 = 8 bf16 (16B); 16 lanes cover the 256B row.
__global__ __launch_bounds__(256) void loss_bf16_kernel(const unsigned short* __restrict__ xn,
                                                        const int* __restrict__ y,
                                                        const int* __restrict__ anchors,
                                                        const int* __restrict__ sampled,
                                                        float* __restrict__ out,
                                                        int S) {
    int a    = blockIdx.x;
    int tid  = threadIdx.x;
    int lane = tid & 15;
    int grp  = tid >> 4;     // 0..15

    int anchor = anchors[a];
    int ya     = y[anchor];
    uint4 ar = *(const uint4*)(xn + (size_t)anchor * DIM + lane * 8);
    float av[8];
    unpack2(ar.x, av[0], av[1]); unpack2(ar.y, av[2], av[3]);
    unpack2(ar.z, av[4], av[5]); unpack2(ar.w, av[6], av[7]);
#pragma unroll
    for (int j = 0; j < 8; ++j) av[j] *= TEMP_INV;   // fold 1/temp into anchor frag

    float num = 0.0f, den = 0.0f, cnt = 0.0f;
    const int* samp = sampled + (size_t)a * S;

#pragma unroll 4
    for (int s = grp; s < S; s += 16) {
        int sidx = samp[s];                           // group-broadcast
        int ys   = y[sidx];
        uint4 sr = *(const uint4*)(xn + (size_t)sidx * DIM + lane * 8);
        float sv[8];
        unpack2(sr.x, sv[0], sv[1]); unpack2(sr.y, sv[2], sv[3]);
        unpack2(sr.z, sv[4], sv[5]); unpack2(sr.w, sv[6], sv[7]);
        float d = 0.0f;
#pragma unroll
        for (int j = 0; j < 8; ++j) d += av[j] * sv[j];
        // 4-step butterfly within the 16-lane group
        d += __shfl_xor(d, 8); d += __shfl_xor(d, 4);
        d += __shfl_xor(d, 2); d += __shfl_xor(d, 1);
        float e = __expf(d);                          // d = sim/temp already
        den += e;
        bool pos = (ys == ya);
        num += pos ? e : 0.0f;
        cnt += pos ? 1.0f : 0.0f;
    }

    __shared__ float sn[16], sd[16], sc[16];
    if (lane == 0) { sn[grp] = num; sd[grp] = den; sc[grp] = cnt; }
    __syncthreads();
    if (tid == 0) {
        float tn = 0.0f, td = 0.0f, tc = 0.0f;
        for (int g = 0; g < 16; ++g) { tn += sn[g]; td += sd[g]; tc += sc[g]; }
        float loss = (tc > 0.0f) ? (-__logf(tn / td) / tc) : 0.0f;
        atomicAdd(out, loss);
    }
}

// ---------------- fp32 fallback (R1 kernels, used only if ws too small) -------

__global__ __launch_bounds__(256) void norm_kernel(const float* __restrict__ x,
                                                   float* __restrict__ inv_norm,
                                                   float* __restrict__ out,
                                                   int N) {
    if (blockIdx.x == 0 && threadIdx.x == 0) out[0] = 0.0f;
    int wave = threadIdx.x >> 6;
    int lane = threadIdx.x & 63;
    int row  = blockIdx.x * 4 + wave;
    if (row >= N) return;
    const float2 v = *(const float2*)(x + (size_t)row * DIM + lane * 2);
    float s = v.x * v.x + v.y * v.y;
    s += __shfl_xor(s, 32); s += __shfl_xor(s, 16); s += __shfl_xor(s, 8);
    s += __shfl_xor(s, 4);  s += __shfl_xor(s, 2);  s += __shfl_xor(s, 1);
    if (lane == 0) inv_norm[row] = rsqrtf(s);
}

__global__ __launch_bounds__(256) void loss_kernel(const float* __restrict__ x,
                                                   const int* __restrict__ y,
                                                   const int* __restrict__ anchors,
                                                   const int* __restrict__ sampled,
                                                   const float* __restrict__ inv_norm,
                                                   float* __restrict__ out,
                                                   int S) {
    int a     = blockIdx.x;
    int tid   = threadIdx.x;
    int lane  = tid & 31;
    int group = tid >> 5;

    int   anchor = anchors[a];
    int   ya     = y[anchor];
    float inv_a  = inv_norm[anchor];
    float4 av = *(const float4*)(x + (size_t)anchor * DIM + lane * 4);
    av.x *= inv_a; av.y *= inv_a; av.z *= inv_a; av.w *= inv_a;

    float num = 0.0f, den = 0.0f, cnt = 0.0f;
    const int* samp = sampled + (size_t)a * S;

#pragma unroll 4
    for (int s = group; s < S; s += 8) {
        int   sidx  = samp[s];
        float inv_s = inv_norm[sidx];
        int   ys    = y[sidx];
        const float4 sv = *(const float4*)(x + (size_t)sidx * DIM + lane * 4);
        float d = av.x * sv.x + av.y * sv.y + av.z * sv.z + av.w * sv.w;
        d += __shfl_xor(d, 16); d += __shfl_xor(d, 8); d += __shfl_xor(d, 4);
        d += __shfl_xor(d, 2);  d += __shfl_xor(d, 1);
        float e = __expf(d * inv_s * TEMP_INV);
        den += e;
        bool pos = (ys == ya);
        num += pos ? e : 0.0f;
        cnt += pos ? 1.0f : 0.0f;
    }

    __shared__ float s_num[8], s_den[8], s_cnt[8];
    if (lane == 0) { s_num[group] = num; s_den[group] = den; s_cnt[group] = cnt; }
    __syncthreads();
    if (tid == 0) {
        float tn = 0.0f, td = 0.0f, tc = 0.0f;
        for (int g = 0; g < 8; ++g) { tn += s_num[g]; td += s_den[g]; tc += s_cnt[g]; }
        float loss = 0.0f;
        if (tc > 0.0f) loss = -__logf(tn / td) / tc;
        atomicAdd(out, loss);
    }
}

extern "C" void kernel_launch(void* const* d_in, const int* in_sizes, int n_in,
                              void* d_out, int out_size, void* d_ws, size_t ws_size,
                              hipStream_t stream) {
    const float* x       = (const float*)d_in[0];
    const int*   y       = (const int*)d_in[1];
    const int*   anchors = (const int*)d_in[2];
    const int*   sampled = (const int*)d_in[3];

    int N = in_sizes[1];
    int A = in_sizes[2];
    int S = in_sizes[3] / A;

    float* out = (float*)d_out;
    size_t need_bf16 = (size_t)N * DIM * sizeof(unsigned short);  // 25.6 MB

    if (ws_size >= need_bf16) {
        unsigned short* xn = (unsigned short*)d_ws;
        int nblocks = (N + 7) / 8;            // 8 rows per 256-thread block
        norm_bf16_kernel<<<nblocks, 256, 0, stream>>>(x, xn, out, N);
        loss_bf16_kernel<<<A, 256, 0, stream>>>(xn, y, anchors, sampled, out, S);
    } else {
        float* inv_norm = (float*)d_ws;       // N floats
        int nblocks = (N + 3) / 4;
        norm_kernel<<<nblocks, 256, 0, stream>>>(x, inv_norm, out, N);
        loss_kernel<<<A, 256, 0, stream>>>(x, y, anchors, sampled, inv_norm, out, S);
    }
}

// Round 3
// 163.332 us; speedup vs baseline: 1.6580x; 1.2196x over previous
//
#include <hip/hip_runtime.h>
#include <math.h>

#define DIM 128
#define TEMP_INV 10.0f

typedef __attribute__((ext_vector_type(2))) float floatx2;

// ---------------- fp8 fast path ----------------
// Normalize rows and quantize to fp8 e4m3 (OCP, HW cvt): one 32-lane group
// per row; lane holds 4 floats -> packs 4 fp8 into one uint.
// Also zeroes d_out[0] (harness re-poisons it to 0xAA before timed replays).
__global__ __launch_bounds__(256) void norm_fp8_kernel(const float* __restrict__ x,
                                                       unsigned int* __restrict__ xq,
                                                       float* __restrict__ out,
                                                       int N) {
    if (blockIdx.x == 0 && threadIdx.x == 0) out[0] = 0.0f;
    int lane = threadIdx.x & 31;
    int grp  = threadIdx.x >> 5;
    int row  = blockIdx.x * 8 + grp;
    if (row >= N) return;
    float4 v = *(const float4*)(x + (size_t)row * DIM + lane * 4);
    float s = v.x*v.x + v.y*v.y + v.z*v.z + v.w*v.w;
    s += __shfl_xor(s, 16); s += __shfl_xor(s, 8); s += __shfl_xor(s, 4);
    s += __shfl_xor(s, 2);  s += __shfl_xor(s, 1);
    float inv = rsqrtf(s);
    int p = 0;
    p = __builtin_amdgcn_cvt_pk_fp8_f32(v.x * inv, v.y * inv, p, false);
    p = __builtin_amdgcn_cvt_pk_fp8_f32(v.z * inv, v.w * inv, p, true);
    xq[(size_t)row * 32 + lane] = (unsigned int)p;
}

static __device__ __forceinline__ float dot16_fp8(const uint4& r, const float* av) {
    floatx2 t;
    float d = 0.0f;
    t = __builtin_amdgcn_cvt_pk_f32_fp8((int)r.x, false); d += av[0]*t.x  + av[1]*t.y;
    t = __builtin_amdgcn_cvt_pk_f32_fp8((int)r.x, true);  d += av[2]*t.x  + av[3]*t.y;
    t = __builtin_amdgcn_cvt_pk_f32_fp8((int)r.y, false); d += av[4]*t.x  + av[5]*t.y;
    t = __builtin_amdgcn_cvt_pk_f32_fp8((int)r.y, true);  d += av[6]*t.x  + av[7]*t.y;
    t = __builtin_amdgcn_cvt_pk_f32_fp8((int)r.z, false); d += av[8]*t.x  + av[9]*t.y;
    t = __builtin_amdgcn_cvt_pk_f32_fp8((int)r.z, true);  d += av[10]*t.x + av[11]*t.y;
    t = __builtin_amdgcn_cvt_pk_f32_fp8((int)r.w, false); d += av[12]*t.x + av[13]*t.y;
    t = __builtin_amdgcn_cvt_pk_f32_fp8((int)r.w, true);  d += av[14]*t.x + av[15]*t.y;
    return d;
}

// One block (256 thr = 32 groups of 8 lanes) per anchor. Lane loads uint4 =
// 16 fp8 (16B); 8 lanes cover the 128B row (2 cache lines). samp + gathered y
// prestaged to LDS once per block at full address-divergence rate.
__global__ __launch_bounds__(256) void loss_fp8_kernel(const unsigned int* __restrict__ xq,
                                                       const int* __restrict__ y,
                                                       const int* __restrict__ anchors,
                                                       const int* __restrict__ sampled,
                                                       float* __restrict__ out,
                                                       int S) {
    int a    = blockIdx.x;
    int tid  = threadIdx.x;
    int lane = tid & 7;
    int grp  = tid >> 3;      // 0..31

    extern __shared__ int sm[];
    int* s_samp = sm;         // [S]
    int* s_y    = sm + S;     // [S]

    const int* samp = sampled + (size_t)a * S;
    for (int i = tid; i < S; i += 256) {
        int si = samp[i];     // coalesced
        s_samp[i] = si;
        s_y[i] = y[si];       // fully-divergent gather, once per block
    }

    int anchor = anchors[a];
    int ya     = y[anchor];
    uint4 ar = *(const uint4*)(xq + (size_t)anchor * 32 + lane * 4);
    float av[16];
    {
        floatx2 t;
        t = __builtin_amdgcn_cvt_pk_f32_fp8((int)ar.x, false); av[0]=t.x;  av[1]=t.y;
        t = __builtin_amdgcn_cvt_pk_f32_fp8((int)ar.x, true);  av[2]=t.x;  av[3]=t.y;
        t = __builtin_amdgcn_cvt_pk_f32_fp8((int)ar.y, false); av[4]=t.x;  av[5]=t.y;
        t = __builtin_amdgcn_cvt_pk_f32_fp8((int)ar.y, true);  av[6]=t.x;  av[7]=t.y;
        t = __builtin_amdgcn_cvt_pk_f32_fp8((int)ar.z, false); av[8]=t.x;  av[9]=t.y;
        t = __builtin_amdgcn_cvt_pk_f32_fp8((int)ar.z, true);  av[10]=t.x; av[11]=t.y;
        t = __builtin_amdgcn_cvt_pk_f32_fp8((int)ar.w, false); av[12]=t.x; av[13]=t.y;
        t = __builtin_amdgcn_cvt_pk_f32_fp8((int)ar.w, true);  av[14]=t.x; av[15]=t.y;
#pragma unroll
        for (int j = 0; j < 16; ++j) av[j] *= TEMP_INV;   // fold 1/temp
    }
    __syncthreads();

    float num = 0.0f, den = 0.0f, cnt = 0.0f;
#pragma unroll 4
    for (int s = grp; s < S; s += 32) {
        int sidx = s_samp[s];     // LDS broadcast within group
        int ys   = s_y[s];
        uint4 sr = *(const uint4*)(xq + (size_t)sidx * 32 + lane * 4);
        float d = dot16_fp8(sr, av);
        d += __shfl_xor(d, 4); d += __shfl_xor(d, 2); d += __shfl_xor(d, 1);
        float e = __expf(d);      // d = sim/temp already
        den += e;
        bool pos = (ys == ya);
        num += pos ? e : 0.0f;
        cnt += pos ? 1.0f : 0.0f;
    }

    __shared__ float sn[32], sd[32], sc[32];
    if (lane == 0) { sn[grp] = num; sd[grp] = den; sc[grp] = cnt; }
    __syncthreads();
    if (tid == 0) {
        float tn = 0.0f, td = 0.0f, tc = 0.0f;
        for (int g = 0; g < 32; ++g) { tn += sn[g]; td += sd[g]; tc += sc[g]; }
        float loss = (tc > 0.0f) ? (-__logf(tn / td) / tc) : 0.0f;
        atomicAdd(out, loss);
    }
}

// ---------------- fp32 fallback (used only if ws too small) ----------------

__global__ __launch_bounds__(256) void norm_kernel(const float* __restrict__ x,
                                                   float* __restrict__ inv_norm,
                                                   float* __restrict__ out,
                                                   int N) {
    if (blockIdx.x == 0 && threadIdx.x == 0) out[0] = 0.0f;
    int wave = threadIdx.x >> 6;
    int lane = threadIdx.x & 63;
    int row  = blockIdx.x * 4 + wave;
    if (row >= N) return;
    const float2 v = *(const float2*)(x + (size_t)row * DIM + lane * 2);
    float s = v.x * v.x + v.y * v.y;
    s += __shfl_xor(s, 32); s += __shfl_xor(s, 16); s += __shfl_xor(s, 8);
    s += __shfl_xor(s, 4);  s += __shfl_xor(s, 2);  s += __shfl_xor(s, 1);
    if (lane == 0) inv_norm[row] = rsqrtf(s);
}

__global__ __launch_bounds__(256) void loss_kernel(const float* __restrict__ x,
                                                   const int* __restrict__ y,
                                                   const int* __restrict__ anchors,
                                                   const int* __restrict__ sampled,
                                                   const float* __restrict__ inv_norm,
                                                   float* __restrict__ out,
                                                   int S) {
    int a     = blockIdx.x;
    int tid   = threadIdx.x;
    int lane  = tid & 31;
    int group = tid >> 5;

    int   anchor = anchors[a];
    int   ya     = y[anchor];
    float inv_a  = inv_norm[anchor];
    float4 av = *(const float4*)(x + (size_t)anchor * DIM + lane * 4);
    av.x *= inv_a; av.y *= inv_a; av.z *= inv_a; av.w *= inv_a;

    float num = 0.0f, den = 0.0f, cnt = 0.0f;
    const int* samp = sampled + (size_t)a * S;

#pragma unroll 4
    for (int s = group; s < S; s += 8) {
        int   sidx  = samp[s];
        float inv_s = inv_norm[sidx];
        int   ys    = y[sidx];
        const float4 sv = *(const float4*)(x + (size_t)sidx * DIM + lane * 4);
        float d = av.x * sv.x + av.y * sv.y + av.z * sv.z + av.w * sv.w;
        d += __shfl_xor(d, 16); d += __shfl_xor(d, 8); d += __shfl_xor(d, 4);
        d += __shfl_xor(d, 2);  d += __shfl_xor(d, 1);
        float e = __expf(d * inv_s * TEMP_INV);
        den += e;
        bool pos = (ys == ya);
        num += pos ? e : 0.0f;
        cnt += pos ? 1.0f : 0.0f;
    }

    __shared__ float s_num[8], s_den[8], s_cnt[8];
    if (lane == 0) { s_num[group] = num; s_den[group] = den; s_cnt[group] = cnt; }
    __syncthreads();
    if (tid == 0) {
        float tn = 0.0f, td = 0.0f, tc = 0.0f;
        for (int g = 0; g < 8; ++g) { tn += s_num[g]; td += s_den[g]; tc += s_cnt[g]; }
        float loss = 0.0f;
        if (tc > 0.0f) loss = -__logf(tn / td) / tc;
        atomicAdd(out, loss);
    }
}

extern "C" void kernel_launch(void* const* d_in, const int* in_sizes, int n_in,
                              void* d_out, int out_size, void* d_ws, size_t ws_size,
                              hipStream_t stream) {
    const float* x       = (const float*)d_in[0];
    const int*   y       = (const int*)d_in[1];
    const int*   anchors = (const int*)d_in[2];
    const int*   sampled = (const int*)d_in[3];

    int N = in_sizes[1];
    int A = in_sizes[2];
    int S = in_sizes[3] / A;

    float* out = (float*)d_out;
    size_t need_fp8 = (size_t)N * DIM;   // 12.8 MB (1 byte/elem)

    if (ws_size >= need_fp8) {
        unsigned int* xq = (unsigned int*)d_ws;
        int nblocks = (N + 7) / 8;
        norm_fp8_kernel<<<nblocks, 256, 0, stream>>>(x, xq, out, N);
        size_t lds = 2 * (size_t)S * sizeof(int);
        loss_fp8_kernel<<<A, 256, lds, stream>>>(xq, y, anchors, sampled, out, S);
    } else {
        float* inv_norm = (float*)d_ws;
        int nblocks = (N + 3) / 4;
        norm_kernel<<<nblocks, 256, 0, stream>>>(x, inv_norm, out, N);
        loss_kernel<<<A, 256, 0, stream>>>(x, y, anchors, sampled, inv_norm, out, S);
    }
}

// Round 4
// 160.568 us; speedup vs baseline: 1.6865x; 1.0172x over previous
//
#include <hip/hip_runtime.h>
#include <math.h>

#define DIM 128
#define TEMP_INV 10.0f

typedef __attribute__((ext_vector_type(2))) float floatx2;

// ---------------- fp8 fast path ----------------
// Normalize rows and quantize to fp8 e4m3 (OCP, HW cvt): one 32-lane group
// per row; lane holds 4 floats -> packs 4 fp8 into one uint.
// Also zeroes d_out[0] (harness re-poisons it to 0xAA before timed replays).
__global__ __launch_bounds__(256) void norm_fp8_kernel(const float* __restrict__ x,
                                                       unsigned int* __restrict__ xq,
                                                       float* __restrict__ out,
                                                       int N) {
    if (blockIdx.x == 0 && threadIdx.x == 0) out[0] = 0.0f;
    int lane = threadIdx.x & 31;
    int grp  = threadIdx.x >> 5;
    int row  = blockIdx.x * 8 + grp;
    if (row >= N) return;
    float4 v = *(const float4*)(x + (size_t)row * DIM + lane * 4);
    float s = v.x*v.x + v.y*v.y + v.z*v.z + v.w*v.w;
    s += __shfl_xor(s, 16); s += __shfl_xor(s, 8); s += __shfl_xor(s, 4);
    s += __shfl_xor(s, 2);  s += __shfl_xor(s, 1);
    float inv = rsqrtf(s);
    int p = 0;
    p = __builtin_amdgcn_cvt_pk_fp8_f32(v.x * inv, v.y * inv, p, false);
    p = __builtin_amdgcn_cvt_pk_fp8_f32(v.z * inv, v.w * inv, p, true);
    xq[(size_t)row * 32 + lane] = (unsigned int)p;
}

// One block (256 thr = 64 groups of 4 lanes) per anchor. Each lane owns a
// 32-element slice of the 128-dim row: 2 x uint4 (16 fp8 each). 4 lanes x 64B
// = one full 128B cache line per load instruction; 2 loads cover the row.
// Anchor slice held unpacked+prescaled in 16 float2 regs (32 VGPR, explicit).
__global__ __launch_bounds__(256) void loss_fp8_kernel(const unsigned int* __restrict__ xq,
                                                       const int* __restrict__ y,
                                                       const int* __restrict__ anchors,
                                                       const int* __restrict__ sampled,
                                                       float* __restrict__ out,
                                                       int S) {
    int a    = blockIdx.x;
    int tid  = threadIdx.x;
    int sub  = tid & 3;       // lane within 4-lane group
    int grp  = tid >> 2;      // 0..63 (group id == sample slot stride)

    extern __shared__ int sm[];
    int* s_samp = sm;         // [S]
    int* s_y    = sm + S;     // [S]

    const int* samp = sampled + (size_t)a * S;
    for (int i = tid; i < S; i += 256) {
        int si = samp[i];     // coalesced
        s_samp[i] = si;
        s_y[i] = y[si];       // fully-divergent gather, once per block
    }

    int anchor = anchors[a];
    int ya     = y[anchor];

    // anchor slice: 8 uints = 32 fp8 -> 16 float2, prescaled by 1/temp
    const unsigned int* arow = xq + (size_t)anchor * 32 + sub * 8;
    uint4 ar0 = *(const uint4*)(arow);
    uint4 ar1 = *(const uint4*)(arow + 4);
    floatx2 av[16];
    {
        unsigned int u[8] = {ar0.x, ar0.y, ar0.z, ar0.w, ar1.x, ar1.y, ar1.z, ar1.w};
#pragma unroll
        for (int k = 0; k < 8; ++k) {
            av[2*k]   = __builtin_amdgcn_cvt_pk_f32_fp8((int)u[k], false);
            av[2*k+1] = __builtin_amdgcn_cvt_pk_f32_fp8((int)u[k], true);
            av[2*k]   *= TEMP_INV;
            av[2*k+1] *= TEMP_INV;
        }
    }
    __syncthreads();

    float num = 0.0f, den = 0.0f, cnt = 0.0f;

#pragma unroll 4
    for (int s = grp; s < S; s += 64) {
        int sidx = s_samp[s];
        int ys   = s_y[s];
        const unsigned int* srow = xq + (size_t)sidx * 32 + sub * 8;
        uint4 r0 = *(const uint4*)(srow);        // independent 16B loads,
        uint4 r1 = *(const uint4*)(srow + 4);    // one 128B line per 4-lane grp
        floatx2 acc2 = {0.0f, 0.0f};
        unsigned int u[8] = {r0.x, r0.y, r0.z, r0.w, r1.x, r1.y, r1.z, r1.w};
#pragma unroll
        for (int k = 0; k < 8; ++k) {
            floatx2 lo = __builtin_amdgcn_cvt_pk_f32_fp8((int)u[k], false);
            floatx2 hi = __builtin_amdgcn_cvt_pk_f32_fp8((int)u[k], true);
            acc2 += av[2*k] * lo;
            acc2 += av[2*k+1] * hi;
        }
        float d = acc2.x + acc2.y;
        d += __shfl_xor(d, 1);                   // 2-step butterfly in 4-lane grp
        d += __shfl_xor(d, 2);
        float e = __expf(d);                     // d = sim/temp already
        den += e;
        bool pos = (ys == ya);
        num += pos ? e : 0.0f;
        cnt += pos ? 1.0f : 0.0f;
    }

    // within 4-lane group all lanes identical; butterfly across the 16 groups
    // of the wave (masks 4..32 never mix within-group lanes -> no overcount)
    num += __shfl_xor(num, 4);  den += __shfl_xor(den, 4);  cnt += __shfl_xor(cnt, 4);
    num += __shfl_xor(num, 8);  den += __shfl_xor(den, 8);  cnt += __shfl_xor(cnt, 8);
    num += __shfl_xor(num, 16); den += __shfl_xor(den, 16); cnt += __shfl_xor(cnt, 16);
    num += __shfl_xor(num, 32); den += __shfl_xor(den, 32); cnt += __shfl_xor(cnt, 32);

    __shared__ float sn[4], sd[4], sc[4];
    int wave = tid >> 6;
    if ((tid & 63) == 0) { sn[wave] = num; sd[wave] = den; sc[wave] = cnt; }
    __syncthreads();
    if (tid == 0) {
        float tn = sn[0] + sn[1] + sn[2] + sn[3];
        float td = sd[0] + sd[1] + sd[2] + sd[3];
        float tc = sc[0] + sc[1] + sc[2] + sc[3];
        float loss = (tc > 0.0f) ? (-__logf(tn / td) / tc) : 0.0f;
        atomicAdd(out, loss);
    }
}

// ---------------- fp32 fallback (used only if ws too small) ----------------

__global__ __launch_bounds__(256) void norm_kernel(const float* __restrict__ x,
                                                   float* __restrict__ inv_norm,
                                                   float* __restrict__ out,
                                                   int N) {
    if (blockIdx.x == 0 && threadIdx.x == 0) out[0] = 0.0f;
    int wave = threadIdx.x >> 6;
    int lane = threadIdx.x & 63;
    int row  = blockIdx.x * 4 + wave;
    if (row >= N) return;
    const float2 v = *(const float2*)(x + (size_t)row * DIM + lane * 2);
    float s = v.x * v.x + v.y * v.y;
    s += __shfl_xor(s, 32); s += __shfl_xor(s, 16); s += __shfl_xor(s, 8);
    s += __shfl_xor(s, 4);  s += __shfl_xor(s, 2);  s += __shfl_xor(s, 1);
    if (lane == 0) inv_norm[row] = rsqrtf(s);
}

__global__ __launch_bounds__(256) void loss_kernel(const float* __restrict__ x,
                                                   const int* __restrict__ y,
                                                   const int* __restrict__ anchors,
                                                   const int* __restrict__ sampled,
                                                   const float* __restrict__ inv_norm,
                                                   float* __restrict__ out,
                                                   int S) {
    int a     = blockIdx.x;
    int tid   = threadIdx.x;
    int lane  = tid & 31;
    int group = tid >> 5;

    int   anchor = anchors[a];
    int   ya     = y[anchor];
    float inv_a  = inv_norm[anchor];
    float4 av = *(const float4*)(x + (size_t)anchor * DIM + lane * 4);
    av.x *= inv_a; av.y *= inv_a; av.z *= inv_a; av.w *= inv_a;

    float num = 0.0f, den = 0.0f, cnt = 0.0f;
    const int* samp = sampled + (size_t)a * S;

#pragma unroll 4
    for (int s = group; s < S; s += 8) {
        int   sidx  = samp[s];
        float inv_s = inv_norm[sidx];
        int   ys    = y[sidx];
        const float4 sv = *(const float4*)(x + (size_t)sidx * DIM + lane * 4);
        float d = av.x * sv.x + av.y * sv.y + av.z * sv.z + av.w * sv.w;
        d += __shfl_xor(d, 16); d += __shfl_xor(d, 8); d += __shfl_xor(d, 4);
        d += __shfl_xor(d, 2);  d += __shfl_xor(d, 1);
        float e = __expf(d * inv_s * TEMP_INV);
        den += e;
        bool pos = (ys == ya);
        num += pos ? e : 0.0f;
        cnt += pos ? 1.0f : 0.0f;
    }

    __shared__ float s_num[8], s_den[8], s_cnt[8];
    if (lane == 0) { s_num[group] = num; s_den[group] = den; s_cnt[group] = cnt; }
    __syncthreads();
    if (tid == 0) {
        float tn = 0.0f, td = 0.0f, tc = 0.0f;
        for (int g = 0; g < 8; ++g) { tn += s_num[g]; td += s_den[g]; tc += s_cnt[g]; }
        float loss = 0.0f;
        if (tc > 0.0f) loss = -__logf(tn / td) / tc;
        atomicAdd(out, loss);
    }
}

extern "C" void kernel_launch(void* const* d_in, const int* in_sizes, int n_in,
                              void* d_out, int out_size, void* d_ws, size_t ws_size,
                              hipStream_t stream) {
    const float* x       = (const float*)d_in[0];
    const int*   y       = (const int*)d_in[1];
    const int*   anchors = (const int*)d_in[2];
    const int*   sampled = (const int*)d_in[3];

    int N = in_sizes[1];
    int A = in_sizes[2];
    int S = in_sizes[3] / A;

    float* out = (float*)d_out;
    size_t need_fp8 = (size_t)N * DIM;   // 12.8 MB (1 byte/elem)

    if (ws_size >= need_fp8) {
        unsigned int* xq = (unsigned int*)d_ws;
        int nblocks = (N + 7) / 8;
        norm_fp8_kernel<<<nblocks, 256, 0, stream>>>(x, xq, out, N);
        size_t lds = 2 * (size_t)S * sizeof(int);
        loss_fp8_kernel<<<A, 256, lds, stream>>>(xq, y, anchors, sampled, out, S);
    } else {
        float* inv_norm = (float*)d_ws;
        int nblocks = (N + 3) / 4;
        norm_kernel<<<nblocks, 256, 0, stream>>>(x, inv_norm, out, N);
        loss_kernel<<<A, 256, 0, stream>>>(x, y, anchors, sampled, inv_norm, out, S);
    }
}